// Round 8
// baseline (71610.773 us; speedup 1.0000x reference)
//
#include <hip/hip_runtime.h>
#include <hip/hip_cooperative_groups.h>

namespace cg = cooperative_groups;

constexpr int   NROWS = 65536;
constexpr int   NK    = 1024;
constexpr float PAv   = 1.0f / 65536.0f;
constexpr float PBv   = 1.0f / 1024.0f;
constexpr float FI    = 1.0f / 1.1f;          // GAMMA/(GAMMA+eps)
constexpr float NEG_INV_EPS = -10.0f;         // -1/eps
constexpr float STOPERR2 = 1e-12f;            // (1e-6)^2 on squared 2-norm
constexpr int   MAXIT = 1000;

// ---------------- cooperative Sinkhorn iteration ----------------
// Geometry: 256 blocks (1/CU; >1 block/CU coop launch REJECTED on HW, r2/3)
// x 512 threads. Staging via global_load_lds (width 16): MLP lives in the
// LDS-DMA FIFO, not VGPRs -> the compiler cannot re-serialize it (it did so
// in r4/r5/r7 at the register level every time).
constexpr int IT_BLOCKS  = 256;
constexpr int IT_THREADS = 512;
constexpr int IT_WAVES   = IT_THREADS / 64;                 // 8
constexpr int IT_RPW     = NROWS / (IT_BLOCKS * IT_WAVES);  // 32 rows per wave
constexpr int NCHUNK     = IT_RPW / 2;                      // 16 chunks of 2 rows

#define VMWAIT(N)  asm volatile("s_waitcnt vmcnt(" #N ")" ::: "memory")
#define LGKMWAIT0  asm volatile("s_waitcnt lgkmcnt(0)" ::: "memory")

typedef const __attribute__((address_space(1))) unsigned int gu32;
typedef __attribute__((address_space(3))) unsigned int       lu32;

// stage one 2-row chunk (8 x global_load_lds dwordx4 = 8 KB) into ldsbuf.
// LDS dest semantics: wave-uniform base, lane i's 16 B lands at base+16*i.
// Global src is per-lane: row_base + lane*16 (+1 KB per segment).
__device__ __forceinline__ void stage2(const float* __restrict__ P, int row,
                                       void* ldsbuf, int lane)
{
  #pragma unroll
  for (int rr = 0; rr < 2; ++rr) {
    const char* g = reinterpret_cast<const char*>(P + (size_t)(row + rr) * NK)
                  + lane * 16;
    char* l = reinterpret_cast<char*>(ldsbuf) + rr * 4096;
    #pragma unroll
    for (int k = 0; k < 4; ++k) {
      __builtin_amdgcn_global_load_lds((gu32*)(g + (k << 10)),
                                       (lu32*)(l + (k << 10)), 16, 0, 0);
    }
  }
}

__global__ __launch_bounds__(IT_THREADS, 2)
void ssk_iter(const float* __restrict__ P, float* __restrict__ cs_ring,
              float* __restrict__ b_out)
{
  cg::grid_group grid = cg::this_grid();
  // [wave][buf][row][4 KB] = 128 KiB staging pool; first 32 KiB double as the
  // wave_cs overlay after the feed loop (staging provably drained: vmcnt(0)).
  __shared__ __align__(16) char pool[IT_WAVES][2][2][4096];
  __shared__ float b_lds[NK];
  __shared__ float redsh[IT_WAVES];
  __shared__ float err_sh;
  float* wcs = reinterpret_cast<float*>(&pool[0][0][0][0]);  // [8][1024] overlay

  const int tid  = threadIdx.x;
  const int wave = tid >> 6;
  const int lane = tid & 63;
  const int row0 = (blockIdx.x * IT_WAVES + wave) * IT_RPW;

  b_lds[tid] = PBv; b_lds[tid + 512] = PBv;   // b0 = 1/K
  __syncthreads();

  stage2(P, row0, &pool[wave][0][0][0], lane);  // chunk 0, iteration 0

  int it = 0;
  for (;;) {
    float* __restrict__ cs_cur = cs_ring + (size_t)(it & 3) * NK;
    {
      // zero the buffer used 2 iters ahead (4-ring; proven r5). Issued first
      // so these stores are the oldest vmem ops and drain before the chunks.
      float* z = cs_ring + (size_t)((it + 2) & 3) * NK;
      z[tid] = 0.0f; z[tid + 512] = 0.0f;
    }

    // lane's 16 columns: 256*k + 4*lane + j (proven layout)
    float bb[16];
    #pragma unroll
    for (int k = 0; k < 4; ++k)
      #pragma unroll
      for (int j = 0; j < 4; ++j)
        bb[4 * k + j] = b_lds[256 * k + 4 * lane + j];

    float acc[16];
    #pragma unroll
    for (int t = 0; t < 16; ++t) acc[t] = 0.0f;

    stage2(P, row0 + 2, &pool[wave][1][0][0], lane);   // chunk 1

    // pipelined feed: compute chunk c (landed), keep chunk c+1 in flight,
    // then refill buf[c&1] with chunk c+2. vmcnt(8) = newest 8 (chunk c+1)
    // may be outstanding; everything older (incl. chunk c) has landed.
    for (int c = 0; c < NCHUNK; ++c) {
      if (c < NCHUNK - 1) { VMWAIT(8); } else { VMWAIT(0); }
      const float4* rA = reinterpret_cast<const float4*>(&pool[wave][c & 1][0][0]);
      const float4* rB = reinterpret_cast<const float4*>(&pool[wave][c & 1][1][0]);
      float4 va[4], vb[4];
      #pragma unroll
      for (int k = 0; k < 4; ++k) {
        va[k] = rA[(k << 6) + lane];
        vb[k] = rB[(k << 6) + lane];
      }
      LGKMWAIT0;   // ds_reads retired -> buffer slots free for the refill below
      #pragma unroll
      for (int k = 0; k < 4; ++k) {
        va[k].x = __expf(va[k].x * NEG_INV_EPS);
        va[k].y = __expf(va[k].y * NEG_INV_EPS);
        va[k].z = __expf(va[k].z * NEG_INV_EPS);
        va[k].w = __expf(va[k].w * NEG_INV_EPS);
        vb[k].x = __expf(vb[k].x * NEG_INV_EPS);
        vb[k].y = __expf(vb[k].y * NEG_INV_EPS);
        vb[k].z = __expf(vb[k].z * NEG_INV_EPS);
        vb[k].w = __expf(vb[k].w * NEG_INV_EPS);
      }
      float dA = 0.f, dB = 0.f;
      #pragma unroll
      for (int k = 0; k < 4; ++k) {
        dA = fmaf(va[k].x, bb[4*k+0], dA);
        dA = fmaf(va[k].y, bb[4*k+1], dA);
        dA = fmaf(va[k].z, bb[4*k+2], dA);
        dA = fmaf(va[k].w, bb[4*k+3], dA);
        dB = fmaf(vb[k].x, bb[4*k+0], dB);
        dB = fmaf(vb[k].y, bb[4*k+1], dB);
        dB = fmaf(vb[k].z, bb[4*k+2], dB);
        dB = fmaf(vb[k].w, bb[4*k+3], dB);
      }
      #pragma unroll
      for (int off = 32; off; off >>= 1) {
        dA += __shfl_xor(dA, off);
        dB += __shfl_xor(dB, off);
      }
      const float aA = PAv / fmaxf(dA, 1e-12f);
      const float aB = PAv / fmaxf(dB, 1e-12f);
      #pragma unroll
      for (int k = 0; k < 4; ++k) {
        acc[4*k+0] = fmaf(aA, va[k].x, acc[4*k+0]);
        acc[4*k+1] = fmaf(aA, va[k].y, acc[4*k+1]);
        acc[4*k+2] = fmaf(aA, va[k].z, acc[4*k+2]);
        acc[4*k+3] = fmaf(aA, va[k].w, acc[4*k+3]);
        acc[4*k+0] = fmaf(aB, vb[k].x, acc[4*k+0]);
        acc[4*k+1] = fmaf(aB, vb[k].y, acc[4*k+1]);
        acc[4*k+2] = fmaf(aB, vb[k].z, acc[4*k+2]);
        acc[4*k+3] = fmaf(aB, vb[k].w, acc[4*k+3]);
      }
      if (c + 2 < NCHUNK)
        stage2(P, row0 + 2 * (c + 2), &pool[wave][c & 1][0][0], lane);
    }
    // here: vmcnt==0 (VMWAIT(0) at last chunk; no stages after c=NCHUNK-3)

    // block-level column reduction through the overlay (staging pool is dead)
    __syncthreads();
    #pragma unroll
    for (int k = 0; k < 4; ++k)
      #pragma unroll
      for (int j = 0; j < 4; ++j)
        wcs[wave * NK + 256 * k + 4 * lane + j] = acc[4 * k + j];
    __syncthreads();
    #pragma unroll
    for (int h = 0; h < 2; ++h) {
      const int c = tid + 512 * h;
      float s = 0.f;
      #pragma unroll
      for (int w = 0; w < IT_WAVES; ++w) s += wcs[w * NK + c];
      atomicAdd(&cs_cur[c], s);
    }
    __syncthreads();   // all overlay reads done -> pool reusable

    // prefetch next iteration's chunk 0 (P is iteration-invariant); the
    // loads fly during barrier arrival skew and are drained by its fence.
    stage2(P, row0, &pool[wave][0][0][0], lane);

    grid.sync();   // the only grid-wide sync per iteration

    // Phase B: every block redundantly (bit-identically) computes b_new + err
    const float c0 = cs_cur[tid], c1 = cs_cur[tid + 512];
    const float bn0 = powf(PBv / fmaxf(c0, 1e-12f), FI);
    const float bn1 = powf(PBv / fmaxf(c1, 1e-12f), FI);
    const float e0 = bn0 - b_lds[tid], e1 = bn1 - b_lds[tid + 512];
    float sq = e0 * e0 + e1 * e1;
    #pragma unroll
    for (int off = 32; off; off >>= 1) sq += __shfl_xor(sq, off);
    if (lane == 0) redsh[wave] = sq;
    __syncthreads();
    if (tid == 0) {
      float s = 0.f;
      #pragma unroll
      for (int w = 0; w < IT_WAVES; ++w) s += redsh[w];
      err_sh = s;
    }
    b_lds[tid] = bn0; b_lds[tid + 512] = bn1;  // own-index write
    ++it;
    __syncthreads();     // publishes err_sh and b_lds
    if (err_sh <= STOPERR2 || it >= MAXIT) break;
  }

  if (blockIdx.x == 0) { b_out[tid] = b_lds[tid]; b_out[tid + 512] = b_lds[tid + 512]; }
}

// ---------------- finalize: OT_plan + partial reductions (proven) ----------
constexpr int FN_BLOCKS  = 2048;
constexpr int FN_THREADS = 256;
constexpr int FN_WAVES   = FN_THREADS / 64;                  // 4
constexpr int FN_RPW     = NROWS / (FN_BLOCKS * FN_WAVES);   // 8

__global__ __launch_bounds__(FN_THREADS)
void ssk_finalize_kernel(const float* __restrict__ P, const float* __restrict__ b_glob,
                         float* __restrict__ out, float* __restrict__ wsum,
                         float* __restrict__ loss_part)
{
  __shared__ float b_sh[NK];
  __shared__ float wave_w[FN_WAVES][NK];
  __shared__ float red[FN_WAVES];

  const int tid  = threadIdx.x;
  const int wave = tid >> 6;
  const int lane = tid & 63;

  #pragma unroll
  for (int i = 0; i < 4; ++i) b_sh[tid + 256 * i] = b_glob[tid + 256 * i];
  __syncthreads();

  float bb[16];
  #pragma unroll
  for (int k = 0; k < 4; ++k)
    #pragma unroll
    for (int j = 0; j < 4; ++j)
      bb[4 * k + j] = b_sh[256 * k + 4 * lane + j];

  float wacc[16];
  #pragma unroll
  for (int t = 0; t < 16; ++t) wacc[t] = 0.0f;
  float lacc = 0.0f;

  const int row0 = (blockIdx.x * FN_WAVES + wave) * FN_RPW;
  float4* out4 = reinterpret_cast<float4*>(out);

  for (int r = 0; r < FN_RPW; ++r) {
    const size_t row = (size_t)(row0 + r);
    const float4* rp = reinterpret_cast<const float4*>(P) + row * (NK / 4);
    float4 pv[4];
    float Q[16];
    float dot = 0.0f;
    #pragma unroll
    for (int k = 0; k < 4; ++k) {
      pv[k] = rp[(k << 6) + lane];
      Q[4*k+0] = __expf(pv[k].x * NEG_INV_EPS);
      Q[4*k+1] = __expf(pv[k].y * NEG_INV_EPS);
      Q[4*k+2] = __expf(pv[k].z * NEG_INV_EPS);
      Q[4*k+3] = __expf(pv[k].w * NEG_INV_EPS);
      dot = fmaf(Q[4*k+0], bb[4*k+0], dot);
      dot = fmaf(Q[4*k+1], bb[4*k+1], dot);
      dot = fmaf(Q[4*k+2], bb[4*k+2], dot);
      dot = fmaf(Q[4*k+3], bb[4*k+3], dot);
    }
    #pragma unroll
    for (int off = 32; off; off >>= 1) dot += __shfl_xor(dot, off);
    const float s = 1.0f / fmaxf(dot, 1e-12f);    // N * a_i  (N*Pa = 1)
    #pragma unroll
    for (int k = 0; k < 4; ++k) {
      float4 o;
      o.x = s * Q[4*k+0] * bb[4*k+0];
      o.y = s * Q[4*k+1] * bb[4*k+1];
      o.z = s * Q[4*k+2] * bb[4*k+2];
      o.w = s * Q[4*k+3] * bb[4*k+3];
      out4[row * (NK / 4) + (k << 6) + lane] = o;
      lacc = fmaf(o.x, pv[k].x, lacc);
      lacc = fmaf(o.y, pv[k].y, lacc);
      lacc = fmaf(o.z, pv[k].z, lacc);
      lacc = fmaf(o.w, pv[k].w, lacc);
      wacc[4*k+0] += o.x; wacc[4*k+1] += o.y; wacc[4*k+2] += o.z; wacc[4*k+3] += o.w;
    }
  }

  #pragma unroll
  for (int k = 0; k < 4; ++k)
    #pragma unroll
    for (int j = 0; j < 4; ++j)
      wave_w[wave][256 * k + 4 * lane + j] = wacc[4 * k + j];
  __syncthreads();
  #pragma unroll
  for (int i = 0; i < 4; ++i) {
    const int c = tid + 256 * i;
    float s2 = wave_w[0][c] + wave_w[1][c] + wave_w[2][c] + wave_w[3][c];
    atomicAdd(&wsum[c], s2);
  }

  #pragma unroll
  for (int off = 32; off; off >>= 1) lacc += __shfl_xor(lacc, off);
  if (lane == 0) red[wave] = lacc;
  __syncthreads();
  if (tid == 0) loss_part[blockIdx.x] = red[0] + red[1] + red[2] + red[3];
}

// ---------------- finish: scalars ----------------
__device__ __forceinline__ float ssk_block_sum_1024(float v, float* red, int wave, int lane)
{
  #pragma unroll
  for (int off = 32; off; off >>= 1) v += __shfl_xor(v, off);
  __syncthreads();
  if (lane == 0) red[wave] = v;
  __syncthreads();
  float t = 0.0f;
  #pragma unroll
  for (int w = 0; w < 16; ++w) t += red[w];
  return t;
}

__global__ __launch_bounds__(1024)
void ssk_finish_kernel(const float* __restrict__ wsum, const float* __restrict__ loss_part,
                       float* __restrict__ out)
{
  __shared__ float red[16];
  const int tid = threadIdx.x, wave = tid >> 6, lane = tid & 63;

  float l  = loss_part[tid] + loss_part[tid + 1024];
  float lt = ssk_block_sum_1024(l, red, wave, lane);

  float wm = wsum[tid] * (1.0f / (float)NROWS);
  float sw = ssk_block_sum_1024(wm, red, wave, lane);
  float wn = wm / (sw + 1e-8f);
  float v  = PBv * (logf(PBv) - logf(wn + 1e-7f));
  float rg = ssk_block_sum_1024(v, red, wave, lane);

  if (tid == 0) {
    out[(size_t)NROWS * NK]     = lt / (float)NROWS;  // ot_loss
    out[(size_t)NROWS * NK + 1] = rg;                 // reg
  }
}

// ---------------- launch ----------------
extern "C" void kernel_launch(void* const* d_in, const int* in_sizes, int n_in,
                              void* d_out, int out_size, void* d_ws, size_t ws_size,
                              hipStream_t stream)
{
  const float* P = (const float*)d_in[0];
  float* out = (float*)d_out;
  float* ws  = (float*)d_ws;

  float* cs_ring   = ws;             // [4][1024]
  float* b_glob    = ws + 4096;      // [1024]
  float* wsum      = ws + 5120;      // [1024]
  float* loss_part = ws + 6144;      // [2048]

  // zero ring + b_glob + wsum every call (deterministic across graph replays)
  hipMemsetAsync(ws, 0, 6144 * sizeof(float), stream);

  void* args[] = { (void*)&P, (void*)&cs_ring, (void*)&b_glob };
  hipLaunchCooperativeKernel((void*)ssk_iter, dim3(IT_BLOCKS), dim3(IT_THREADS),
                             args, 0, stream);

  ssk_finalize_kernel<<<dim3(FN_BLOCKS), dim3(FN_THREADS), 0, stream>>>(
      P, b_glob, out, wsum, loss_part);
  ssk_finish_kernel<<<dim3(1), dim3(1024), 0, stream>>>(wsum, loss_part, out);
}